// Round 4
// baseline (164.560 us; speedup 1.0000x reference)
//
#include <hip/hip_runtime.h>
#include <hip/hip_bf16.h>
#include <math.h>

// dtypes for MFMA
typedef __bf16 bf16x8 __attribute__((ext_vector_type(8)));
typedef float  f32x16 __attribute__((ext_vector_type(16)));

// ---- workspace layout (float offsets) ----
// wfrag : 65536 bf16 (fragment-ready W)          [0, 32768)
// wlast : 256 fp32 (column 256 of conv_w)        [32768, 33024)
// accA  : [128][256] fp32                        [65792, 98560)
// accX  : [128][256] fp32                        [98560, 131328)
#define WLAST_OFF 32768
#define ACCA_OFF  65792
#define ACCX_OFF  98560

static __device__ __forceinline__ unsigned f2bf_u(float f) {
    unsigned u = __builtin_bit_cast(unsigned, f);
    return (u + 0x7fffu + ((u >> 16) & 1u)) >> 16;                     // RNE
}
// packed bf16 pair via HW cvt (memcpy: __hip_bfloat162 not trivially copyable)
static __device__ __forceinline__ unsigned pkbf(float a, float b) {
    __hip_bfloat162 h = __float22bfloat162_rn(make_float2(a, b));      // a in low 16
    unsigned u; __builtin_memcpy(&u, &h, 4); return u;
}

// Barrier WITHOUT vmcnt drain: LDS produced by reg->ds_write only (no
// global_load_lds), so lgkmcnt(0)+s_barrier is sufficient for LDS visibility
// while prefetch global->reg loads stay in flight across the barrier.
static __device__ __forceinline__ void barrier_lds() {
    asm volatile("s_waitcnt lgkmcnt(0)\n\ts_barrier" ::: "memory");
}

// DPP cross-lane add (all-VALU, no LDS pipe)
template<int CTRL, int RM>
static __device__ __forceinline__ float dpp_add(float x) {
    int yi = __builtin_amdgcn_update_dpp(0, __builtin_bit_cast(int, x), CTRL, RM, 0xF, true);
    return x + __builtin_bit_cast(float, yi);
}
// 32-lane (half-wave) sum; valid in lanes 16-31 / 48-63; lane 31/63 used.
static __device__ __forceinline__ float red32(float x) {
    x = dpp_add<0x121, 0xF>(x);   // row_ror:1
    x = dpp_add<0x122, 0xF>(x);   // row_ror:2
    x = dpp_add<0x124, 0xF>(x);   // row_ror:4
    x = dpp_add<0x128, 0xF>(x);   // row_ror:8
    x = dpp_add<0x142, 0xA>(x);   // row_bcast15 into rows 1,3
    return x;
}

// k_init: fragment-ready bf16 W + wlast + zero accumulators (needed each launch:
// k_main accumulates via atomics).
// A-frag (32x32x16): lane l holds A[o = ot*32 + (l&31)][k = S*16 + (l>>5)*8 + j].
__global__ void k_init(const float* __restrict__ conv_w, float* __restrict__ ws) {
    int bk = blockIdx.x;
    int tid = threadIdx.x;
    int idx = bk * 256 + tid;                   // 0..65535
    int j  = idx & 7;
    int l  = (idx >> 3) & 63;
    int ot = (idx >> 9) & 7;
    int S  = idx >> 12;                         // 0..15
    int o  = ot * 32 + (l & 31);
    int k  = S * 16 + (l >> 5) * 8 + j;
    ((unsigned short*)ws)[idx] = (unsigned short)f2bf_u(conv_w[o * 257 + k]);
    if (idx < 256) ws[WLAST_OFF + idx] = conv_w[idx * 257 + 256];
    ws[ACCA_OFF + idx] = 0.0f;                  // zeroes accA then accX (65536 floats)
}

// k_main: 256 blocks = 1/CU; block = (image xb, hw-half = 512 positions),
// 8 chunks of 64 hw. Double-buffered sx: each chunk iteration is
//   regionA = [MFMA(t) | convert(t+1)->other buf | prefetch(t+2)]  (pipes overlap)
//   barrier; regionB = [wave0 dot-finalize(t+1) | epilogue(t)]; barrier.
// dotf double-buffered with 1-chunk lag -> only 2 lgkm-barriers per chunk.
// Epilogue x-extraction via ds_read_b64 (4 o per read) -> 4x fewer LDS ops.
__global__ __launch_bounds__(512, 2)
void k_main(const float* __restrict__ x1, const float* __restrict__ x2,
            float* __restrict__ ws) {
    int bx = blockIdx.x;               // 0..255
    int xb = bx >> 1;                  // image 0..127
    int half = bx & 1;                 // hw half: 512 positions
    const float* xpi = ((xb < 64) ? x1 : x2) + (size_t)(xb & 63) * (256 * 1024);
    const unsigned short* wfrag = (const unsigned short*)ws;
    float* accA = ws + ACCA_OFF + xb * 256;
    float* accX = ws + ACCX_OFF + xb * 256;

    int tid = threadIdx.x;
    int w = tid >> 6;                  // wave 0..7 (owns o = w*32 .. w*32+31)
    int l = tid & 63;
    int lw = l & 31, q = l >> 5;

    // [buf][S][hw][word] bf16-pair tile; word swizzle: phys = log ^ ((hw>>4)&1)<<2
    __shared__ __align__(16) unsigned sx[2][16][64][8];   // 64 KB double buffer
    __shared__ float sd[64][9];        // dot partials, one col per wave
    __shared__ float swl[256];         // W last column
    __shared__ float scen[256];        // this image's center pixels
    __shared__ float dotf[2][64];      // finalized dot, double-buffered by chunk&1

    int hwi = tid & 15, kc = tid >> 4; // thread: hw hwi*4..+3, channels {2kc,2kc+1}+64s

    // ---- prologue: centers + wlast -> LDS; A-frags -> regs; chunk-0 x -> regs ----
    float cenv = 0.f, wlv = 0.f;
    if (tid < 256) {
        cenv = xpi[(size_t)tid * 1024 + 528];          // x[tid][16][16]
        wlv  = ws[WLAST_OFF + tid];
    }
    const unsigned short* ap = wfrag + (size_t)(w * 64 + l) * 8;
    bf16x8 A[16];
    #pragma unroll
    for (int S = 0; S < 16; ++S)
        A[S] = *(const bf16x8*)(ap + (size_t)S * 4096);

    const float* xbase = xpi + half * 512 + (size_t)(kc * 2) * 1024 + hwi * 4;
    float4 xv[8];
    #pragma unroll
    for (int s = 0; s < 4; ++s) {
        xv[2 * s]     = *(const float4*)(xbase + (size_t)(64 * s) * 1024);
        xv[2 * s + 1] = *(const float4*)(xbase + (size_t)(64 * s + 1) * 1024);
    }
    if (tid < 256) { scen[tid] = cenv; swl[tid] = wlv; }
    barrier_lds();                                     // scen/swl visible

    int sig = ((lw >> 4) & 1) << 2;                    // same for rows lw, 32+lw

    // convert chunk `ct` (data in xv) into sx[buf]; dot partials -> sd
    auto do_convert = [&](int buf) {
        float dotp[4] = {0.f, 0.f, 0.f, 0.f};
        #pragma unroll
        for (int s = 0; s < 4; ++s) {
            float4 e = xv[2 * s], o4 = xv[2 * s + 1];
            int c = kc * 2 + 64 * s;
            float s0 = scen[c], s1 = scen[c + 1];
            dotp[0] += e.x * s0 + o4.x * s1;
            dotp[1] += e.y * s0 + o4.y * s1;
            dotp[2] += e.z * s0 + o4.z * s1;
            dotp[3] += e.w * s0 + o4.w * s1;
            int S  = (kc >> 3) + 4 * s;
            int wd = kc & 7;
            float ee[4] = {e.x, e.y, e.z, e.w};
            float oo[4] = {o4.x, o4.y, o4.z, o4.w};
            #pragma unroll
            for (int j = 0; j < 4; ++j) {
                int jj  = (hwi + j) & 3;               // rotate rows (2-way write)
                int hwr = hwi * 4 + jj;
                sx[buf][S][hwr][wd ^ (((hwr >> 4) & 1) << 2)] = pkbf(ee[jj], oo[jj]);
            }
        }
        #pragma unroll
        for (int j = 0; j < 4; ++j) {                  // intra-wave pre-reduce
            float v = dotp[j];
            v += __shfl_xor(v, 16, 64);
            v += __shfl_xor(v, 32, 64);
            dotp[j] = v;
        }
        if (l < 16) {
            #pragma unroll
            for (int j = 0; j < 4; ++j) sd[hwi * 4 + j][w] = dotp[j];
        }
    };
    auto do_prefetch = [&](int ct) {
        const float* xn = xbase + ct * 64;
        #pragma unroll
        for (int s = 0; s < 4; ++s) {
            xv[2 * s]     = *(const float4*)(xn + (size_t)(64 * s) * 1024);
            xv[2 * s + 1] = *(const float4*)(xn + (size_t)(64 * s + 1) * 1024);
        }
    };

    // ---- peel: convert chunk 0, finalize dotf[0] ----
    do_convert(0);
    do_prefetch(1);
    barrier_lds();
    if (tid < 64) {
        float ssum = 0.f;
        #pragma unroll
        for (int k2 = 0; k2 < 8; ++k2) ssum += sd[tid][k2];
        dotf[0][tid] = ssum * (1.0f / 256.0f);
    }
    barrier_lds();

    float sA[16], sX[16];
    #pragma unroll
    for (int r = 0; r < 16; ++r) { sA[r] = 0.f; sX[r] = 0.f; }

    #pragma unroll 1
    for (int t = 0; t < 8; ++t) {
        int cur = t & 1, nxt = cur ^ 1;

        // ================= region A: MFMA(t) | convert(t+1) | prefetch(t+2) ====
        f32x16 acc0, acc1;
        #pragma unroll
        for (int e = 0; e < 16; ++e) { acc0[e] = 0.0f; acc1[e] = 0.0f; }
        const unsigned* b0p = &sx[cur][0][lw][(q * 4) ^ sig];
        const unsigned* b1p = &sx[cur][0][32 + lw][(q * 4) ^ sig];
        #pragma unroll
        for (int S = 0; S < 16; ++S) {
            bf16x8 b0, b1;
            __builtin_memcpy(&b0, b0p + S * 512, 16);  // byte off = S*2048 (imm)
            __builtin_memcpy(&b1, b1p + S * 512, 16);
            acc0 = __builtin_amdgcn_mfma_f32_32x32x16_bf16(A[S], b0, acc0, 0, 0, 0);
            acc1 = __builtin_amdgcn_mfma_f32_32x32x16_bf16(A[S], b1, acc1, 0, 0, 0);
        }
        if (t < 7) do_convert(nxt);                    // chunk t+1 -> other buffer
        if (t < 6) do_prefetch(t + 2);                 // loads fly across barriers
        barrier_lds();                                 // B1

        // ================= region B: dot-finalize(t+1) | epilogue(t) ===========
        if (t < 7 && tid < 64) {
            float ssum = 0.f;
            #pragma unroll
            for (int k2 = 0; k2 < 8; ++k2) ssum += sd[tid][k2];
            dotf[nxt][tid] = ssum * (1.0f / 256.0f);
        }
        float dv0 = dotf[cur][lw];
        float dv1 = dotf[cur][32 + lw];
        #pragma unroll
        for (int m = 0; m < 4; ++m) {                  // o-quads: 4 o per b64 read
            int ob = w * 32 + 8 * m + 4 * q;           // even; quad stays in one Si
            int Si = ob >> 4;
            int Wp = ((ob >> 1) & 7) ^ sig;            // even -> b64-aligned
            unsigned u0[2], u1[2];
            __builtin_memcpy(u0, &sx[cur][Si][lw][Wp], 8);
            __builtin_memcpy(u1, &sx[cur][Si][32 + lw][Wp], 8);
            #pragma unroll
            for (int d = 0; d < 4; ++d) {
                int r = 4 * m + d;                     // row = 8m+4q+d (C/D layout)
                int o = ob + d;
                float wl = swl[o];
                float z0 = acc0[r] + wl * dv0;
                float z1 = acc1[r] + wl * dv1;
                float a0s = __builtin_amdgcn_rcpf(1.0f + __expf(-z0));
                float a1s = __builtin_amdgcn_rcpf(1.0f + __expf(-z1));
                unsigned wa = (d & 2) ? u0[1] : u0[0];
                unsigned wb = (d & 2) ? u1[1] : u1[0];
                float xv0 = (d & 1) ? __builtin_bit_cast(float, wa & 0xffff0000u)
                                    : __builtin_bit_cast(float, wa << 16);
                float xv1 = (d & 1) ? __builtin_bit_cast(float, wb & 0xffff0000u)
                                    : __builtin_bit_cast(float, wb << 16);
                sA[r] += a0s + a1s;
                sX[r] += a0s * xv0 + a1s * xv1;
            }
        }
        barrier_lds();                                 // B2: sx[cur]/dotf reusable
    }

    // ---- final: one DPP reduce + one atomic pair per o for the whole block ----
    #pragma unroll
    for (int r = 0; r < 16; ++r) {
        int row = (r & 3) + 8 * (r >> 2) + 4 * q;
        int o = w * 32 + row;
        float rA = red32(sA[r]);
        float rX = red32(sX[r]);
        if (lw == 31) {                                // lanes 31,63 hold sums
            atomicAdd(&accA[o], rA);
            atomicAdd(&accX[o], rX);
        }
    }
}

// out[b,o] = accX0/(accA0+eps) + accX1/(accA1+eps)
__global__ void k_out(const float* __restrict__ ws, float* __restrict__ out) {
    int idx = blockIdx.x * 256 + threadIdx.x;     // b*256 + o
    int b = idx >> 8, o = idx & 255;
    float a0 = ws[ACCA_OFF + b * 256 + o];
    float p0 = ws[ACCX_OFF + b * 256 + o];
    float a1 = ws[ACCA_OFF + (64 + b) * 256 + o];
    float p1 = ws[ACCX_OFF + (64 + b) * 256 + o];
    out[idx] = p0 / (a0 + 1e-8f) + p1 / (a1 + 1e-8f);
}

extern "C" void kernel_launch(void* const* d_in, const int* in_sizes, int n_in,
                              void* d_out, int out_size, void* d_ws, size_t ws_size,
                              hipStream_t stream) {
    const float* x1     = (const float*)d_in[0];
    const float* x2     = (const float*)d_in[1];
    const float* conv_w = (const float*)d_in[2];
    // d_in[3..6] (caLayer params) are dead: softmax over a size-1 axis == 1.
    float* ws  = (float*)d_ws;
    float* out = (float*)d_out;

    k_init<<<256, 256, 0, stream>>>(conv_w, ws);
    k_main<<<256, 512, 0, stream>>>(x1, x2, ws);
    k_out<<<64, 256, 0, stream>>>(ws, out);
}